// Round 6
// baseline (675.765 us; speedup 1.0000x reference)
//
#include <hip/hip_runtime.h>
#include <hip/hip_bf16.h>
#include <math.h>

#define NEG_SLOPE 0.2f
#define SCAN_BLOCK 256

// ---------------- utility ----------------
__global__ __launch_bounds__(256) void zero_int_kernel(int* __restrict__ p, int n) {
    int i = blockIdx.x * 256 + threadIdx.x;
    if (i < n) p[i] = 0;
}

// ---------------- CSR build ----------------
__global__ __launch_bounds__(256) void count_deg_kernel(const int* __restrict__ dst,
                                                        int E, int N, int* __restrict__ deg) {
    int e = blockIdx.x * 256 + threadIdx.x;
    int Etot = E + N;
    if (e >= Etot) return;
    int d = (e < E) ? dst[e] : (e - E);
    atomicAdd(&deg[d], 1);
}

// 3-phase scan: (A) per-block partial sums, (B) scan partials, (C) final scan.
__global__ __launch_bounds__(SCAN_BLOCK) void deg_partial_kernel(const int* __restrict__ deg,
                                                                 int* __restrict__ part, int N) {
    __shared__ int red[SCAN_BLOCK];
    int t = threadIdx.x;
    int i = blockIdx.x * SCAN_BLOCK + t;
    red[t] = (i < N) ? deg[i] : 0;
    __syncthreads();
    #pragma unroll
    for (int off = SCAN_BLOCK / 2; off > 0; off >>= 1) {
        if (t < off) red[t] += red[t + off];
        __syncthreads();
    }
    if (t == 0) part[blockIdx.x] = red[0];
}

__global__ __launch_bounds__(1024) void scan_part_kernel(int* __restrict__ part, int nPart) {
    __shared__ int s[1024];
    int t = threadIdx.x;
    int v = (t < nPart) ? part[t] : 0;
    s[t] = v;
    __syncthreads();
    for (int off = 1; off < 1024; off <<= 1) {
        int u = (t >= off) ? s[t - off] : 0;
        __syncthreads();
        s[t] += u;
        __syncthreads();
    }
    if (t < nPart) part[t] = (t == 0) ? 0 : s[t - 1];   // exclusive block offsets
}

__global__ __launch_bounds__(SCAN_BLOCK) void scan_final_kernel(const int* __restrict__ deg,
                                                                const int* __restrict__ part,
                                                                int* __restrict__ row_ptr, int N) {
    __shared__ int s[SCAN_BLOCK];
    int t = threadIdx.x;
    int i = blockIdx.x * SCAN_BLOCK + t;
    int v = (i < N) ? deg[i] : 0;
    s[t] = v;
    __syncthreads();
    #pragma unroll
    for (int off = 1; off < SCAN_BLOCK; off <<= 1) {
        int u = (t >= off) ? s[t - off] : 0;
        __syncthreads();
        s[t] += u;
        __syncthreads();
    }
    int incl = s[t];
    int base = part[blockIdx.x];
    if (i < N) row_ptr[i] = base + incl - v;
    if (i == N - 1) row_ptr[N] = base + incl;
}

__global__ __launch_bounds__(256) void scatter_kernel(const int* __restrict__ src,
                                                      const int* __restrict__ dst,
                                                      int E, int N,
                                                      const int* __restrict__ row_ptr,
                                                      int* __restrict__ cursor,
                                                      int* __restrict__ col_src) {
    int e = blockIdx.x * 256 + threadIdx.x;
    int Etot = E + N;
    if (e >= Etot) return;
    int d, s;
    if (e < E) { d = dst[e]; s = src[e]; } else { d = e - E; s = e - E; }
    int pos = atomicAdd(&cursor[d], 1);
    col_src[row_ptr[d] + pos] = s;
}

// ---------------- GEMM + fused attention dots ----------------
// Y[N,128] = X[N,128] @ W[128,128]; also writes asrc/adst.
// heads==8: each thread owns 2 whole heads (16 ch each) of its 32 channels.
// heads==1: 4-thread shfl reduce over the row group.
__global__ __launch_bounds__(256) void gemm_att_kernel(const float* __restrict__ X,
                                                       const float* __restrict__ W,
                                                       const float* __restrict__ attS,
                                                       const float* __restrict__ attD,
                                                       float* __restrict__ Y,
                                                       float* __restrict__ asrc,
                                                       float* __restrict__ adst,
                                                       int N, int heads) {
    __shared__ float Ws[128 * 128];
    __shared__ float attSs[128], attDs[128];
    int tid = threadIdx.x;
    {
        const float4* W4 = (const float4*)W;
        float4* Ws4 = (float4*)Ws;
        #pragma unroll
        for (int i = 0; i < 16; ++i) Ws4[tid + i * 256] = W4[tid + i * 256];
        if (tid < 128) { attSs[tid] = attS[tid]; attDs[tid] = attD[tid]; }
    }
    __syncthreads();
    int r = blockIdx.x * 64 + (tid >> 2);
    int c0 = (tid & 3) * 32;
    if (r >= N) return;
    float acc[32];
    #pragma unroll
    for (int j = 0; j < 32; ++j) acc[j] = 0.f;
    const float4* Xrow = (const float4*)(X + (size_t)r * 128);
    for (int k4 = 0; k4 < 32; ++k4) {
        float4 xv = Xrow[k4];
        #pragma unroll
        for (int kk = 0; kk < 4; ++kk) {
            float xk = (kk == 0) ? xv.x : (kk == 1) ? xv.y : (kk == 2) ? xv.z : xv.w;
            const float4* wrow = (const float4*)(Ws + (k4 * 4 + kk) * 128 + c0);
            #pragma unroll
            for (int j4 = 0; j4 < 8; ++j4) {
                float4 wv = wrow[j4];
                acc[j4 * 4 + 0] = fmaf(xk, wv.x, acc[j4 * 4 + 0]);
                acc[j4 * 4 + 1] = fmaf(xk, wv.y, acc[j4 * 4 + 1]);
                acc[j4 * 4 + 2] = fmaf(xk, wv.z, acc[j4 * 4 + 2]);
                acc[j4 * 4 + 3] = fmaf(xk, wv.w, acc[j4 * 4 + 3]);
            }
        }
    }
    float4* Yrow = (float4*)(Y + (size_t)r * 128 + c0);
    #pragma unroll
    for (int j4 = 0; j4 < 8; ++j4)
        Yrow[j4] = make_float4(acc[j4 * 4 + 0], acc[j4 * 4 + 1], acc[j4 * 4 + 2], acc[j4 * 4 + 3]);

    // fused attention dots
    if (heads == 8) {
        float s0 = 0.f, s1 = 0.f, d0 = 0.f, d1 = 0.f;
        #pragma unroll
        for (int j = 0; j < 16; ++j) {
            s0 = fmaf(acc[j],      attSs[c0 + j],      s0);
            d0 = fmaf(acc[j],      attDs[c0 + j],      d0);
            s1 = fmaf(acc[j + 16], attSs[c0 + j + 16], s1);
            d1 = fmaf(acc[j + 16], attDs[c0 + j + 16], d1);
        }
        int h0 = c0 >> 4;   // {0,2,4,6}
        asrc[r * 8 + h0]     = s0;
        asrc[r * 8 + h0 + 1] = s1;
        adst[r * 8 + h0]     = d0;
        adst[r * 8 + h0 + 1] = d1;
    } else {
        float sp = 0.f, dp = 0.f;
        #pragma unroll
        for (int j = 0; j < 32; ++j) {
            sp = fmaf(acc[j], attSs[c0 + j], sp);
            dp = fmaf(acc[j], attDs[c0 + j], dp);
        }
        sp += __shfl_xor(sp, 1, 64); sp += __shfl_xor(sp, 2, 64);
        dp += __shfl_xor(dp, 1, 64); dp += __shfl_xor(dp, 2, 64);
        if ((tid & 3) == 0) { asrc[r] = sp; adst[r] = dp; }
    }
}

// ---------------- layer-1 aggregation: online softmax, one wave per node ----------------
__global__ __launch_bounds__(256) void agg1_kernel(const float* __restrict__ xh,
                                                   const float* __restrict__ asrc,
                                                   const float* __restrict__ adst,
                                                   const int* __restrict__ row_ptr,
                                                   const int* __restrict__ col_src,
                                                   const float* __restrict__ b1,
                                                   float* __restrict__ out, int N) {
    int node = blockIdx.x * 4 + (threadIdx.x >> 6);
    int lane = threadIdx.x & 63;
    if (node >= N) return;
    int h1 = lane >> 4;                 // head of value v1=lane; v2=lane+64 -> head h1+4
    float ad1 = adst[node * 8 + h1];
    float ad2 = adst[node * 8 + h1 + 4];
    int beg = row_ptr[node], end = row_ptr[node + 1];
    float m1 = -INFINITY, m2 = -INFINITY;
    float s1 = 0.f, s2 = 0.f, a1 = 0.f, a2 = 0.f;
    for (int e = beg; e < end; ++e) {
        int sv = col_src[e];
        float e1 = asrc[sv * 8 + h1] + ad1;
        float e2 = asrc[sv * 8 + h1 + 4] + ad2;
        e1 = (e1 > 0.f) ? e1 : NEG_SLOPE * e1;
        e2 = (e2 > 0.f) ? e2 : NEG_SLOPE * e2;
        float x1 = xh[(size_t)sv * 128 + lane];
        float x2 = xh[(size_t)sv * 128 + lane + 64];
        if (e1 > m1) { float r = __expf(m1 - e1); s1 *= r; a1 *= r; m1 = e1; }
        float p1 = __expf(e1 - m1);
        s1 += p1; a1 = fmaf(p1, x1, a1);
        if (e2 > m2) { float r = __expf(m2 - e2); s2 *= r; a2 *= r; m2 = e2; }
        float p2 = __expf(e2 - m2);
        s2 += p2; a2 = fmaf(p2, x2, a2);
    }
    float o1 = a1 / s1 + b1[lane];
    float o2 = a2 / s2 + b1[lane + 64];
    // ELU
    o1 = (o1 > 0.f) ? o1 : (__expf(o1) - 1.f);
    o2 = (o2 > 0.f) ? o2 : (__expf(o2) - 1.f);
    out[(size_t)node * 128 + lane]      = o1;
    out[(size_t)node * 128 + lane + 64] = o2;
}

// ---------------- layer-2 aggregation (H=1) ----------------
__global__ __launch_bounds__(256) void agg2_kernel(const float* __restrict__ xh,
                                                   const float* __restrict__ asrc,
                                                   const float* __restrict__ adst,
                                                   const int* __restrict__ row_ptr,
                                                   const int* __restrict__ col_src,
                                                   const float* __restrict__ b2,
                                                   float* __restrict__ out, int N) {
    int node = blockIdx.x * 4 + (threadIdx.x >> 6);
    int lane = threadIdx.x & 63;
    if (node >= N) return;
    float ad = adst[node];
    int beg = row_ptr[node], end = row_ptr[node + 1];
    float m = -INFINITY, s = 0.f, a1 = 0.f, a2 = 0.f;
    for (int e = beg; e < end; ++e) {
        int sv = col_src[e];
        float al = asrc[sv] + ad;
        al = (al > 0.f) ? al : NEG_SLOPE * al;
        float x1 = xh[(size_t)sv * 128 + lane];
        float x2 = xh[(size_t)sv * 128 + lane + 64];
        if (al > m) { float r = __expf(m - al); s *= r; a1 *= r; a2 *= r; m = al; }
        float p = __expf(al - m);
        s += p;
        a1 = fmaf(p, x1, a1);
        a2 = fmaf(p, x2, a2);
    }
    out[(size_t)node * 128 + lane]      = a1 / s + b2[lane];
    out[(size_t)node * 128 + lane + 64] = a2 / s + b2[lane + 64];
}

// ---------------- launch ----------------
extern "C" void kernel_launch(void* const* d_in, const int* in_sizes, int n_in,
                              void* d_out, int out_size, void* d_ws, size_t ws_size,
                              hipStream_t stream) {
    const float* x        = (const float*)d_in[0];
    const int*   src      = (const int*)d_in[1];
    const int*   dst      = (const int*)d_in[2];
    const float* W1       = (const float*)d_in[3];
    const float* att_src1 = (const float*)d_in[4];
    const float* att_dst1 = (const float*)d_in[5];
    const float* b1       = (const float*)d_in[6];
    const float* W2       = (const float*)d_in[7];
    const float* att_src2 = (const float*)d_in[8];
    const float* att_dst2 = (const float*)d_in[9];
    const float* b2       = (const float*)d_in[10];

    const int N = in_sizes[0] / 128;
    const int E = in_sizes[1];
    const int Etot = E + N;

    float* fws   = (float*)d_ws;
    float* xh    = fws;                    // N*128 (reused for both layers)
    float* asrc1 = xh + (size_t)N * 128;   // N*8
    float* adst1 = asrc1 + (size_t)N * 8;  // N*8
    float* asrc2 = adst1 + (size_t)N * 8;  // N
    float* adst2 = asrc2 + N;              // N
    int*   deg     = (int*)(adst2 + N);    // N
    int*   cursor  = deg + N;              // N
    int*   row_ptr = cursor + N;           // N+1
    int*   col_src = row_ptr + N + 1;      // Etot
    int*   part    = col_src + Etot;       // <=1024

    float* h = (float*)d_out;              // layer-1 output lives in d_out

    const int nodeBlocks = (N + 3) / 4;
    const int edgeBlocks = (Etot + 255) / 256;
    const int gemmBlocks = (N + 63) / 64;
    const int scanBlocks = (N + SCAN_BLOCK - 1) / SCAN_BLOCK;   // 196 <= 1024

    // CSR build (shared by both layers)
    zero_int_kernel<<<(2 * N + 255) / 256, 256, 0, stream>>>(deg, 2 * N);
    count_deg_kernel<<<edgeBlocks, 256, 0, stream>>>(dst, E, N, deg);
    deg_partial_kernel<<<scanBlocks, SCAN_BLOCK, 0, stream>>>(deg, part, N);
    scan_part_kernel<<<1, 1024, 0, stream>>>(part, scanBlocks);
    scan_final_kernel<<<scanBlocks, SCAN_BLOCK, 0, stream>>>(deg, part, row_ptr, N);
    scatter_kernel<<<edgeBlocks, 256, 0, stream>>>(src, dst, E, N, row_ptr, cursor, col_src);

    // Layer 1 (GEMM + fused attention dots)
    gemm_att_kernel<<<gemmBlocks, 256, 0, stream>>>(x, W1, att_src1, att_dst1, xh, asrc1, adst1, N, 8);
    agg1_kernel<<<nodeBlocks, 256, 0, stream>>>(xh, asrc1, adst1, row_ptr, col_src, b1, h, N);

    // Layer 2
    gemm_att_kernel<<<gemmBlocks, 256, 0, stream>>>(h, W2, att_src2, att_dst2, xh, asrc2, adst2, N, 1);
    agg2_kernel<<<nodeBlocks, 256, 0, stream>>>(xh, asrc2, adst2, row_ptr, col_src, b2, (float*)d_out, N);
}

// Round 7
// 340.858 us; speedup vs baseline: 1.9825x; 1.9825x over previous
//
#include <hip/hip_runtime.h>
#include <hip/hip_bf16.h>
#include <math.h>

#define NEG_SLOPE 0.2f
#define SCAN_BLOCK 256
#define BK 32

// ---------------- utility ----------------
__global__ __launch_bounds__(256) void zero_int_kernel(int* __restrict__ p, int n) {
    int i = blockIdx.x * 256 + threadIdx.x;
    if (i < n) p[i] = 0;
}

// ---------------- CSR build ----------------
__global__ __launch_bounds__(256) void count_deg_kernel(const int* __restrict__ dst,
                                                        int E, int N, int* __restrict__ deg) {
    int e = blockIdx.x * 256 + threadIdx.x;
    int Etot = E + N;
    if (e >= Etot) return;
    int d = (e < E) ? dst[e] : (e - E);
    atomicAdd(&deg[d], 1);
}

__global__ __launch_bounds__(SCAN_BLOCK) void deg_partial_kernel(const int* __restrict__ deg,
                                                                 int* __restrict__ part, int N) {
    __shared__ int red[SCAN_BLOCK];
    int t = threadIdx.x;
    int i = blockIdx.x * SCAN_BLOCK + t;
    red[t] = (i < N) ? deg[i] : 0;
    __syncthreads();
    #pragma unroll
    for (int off = SCAN_BLOCK / 2; off > 0; off >>= 1) {
        if (t < off) red[t] += red[t + off];
        __syncthreads();
    }
    if (t == 0) part[blockIdx.x] = red[0];
}

__global__ __launch_bounds__(1024) void scan_part_kernel(int* __restrict__ part, int nPart) {
    __shared__ int s[1024];
    int t = threadIdx.x;
    int v = (t < nPart) ? part[t] : 0;
    s[t] = v;
    __syncthreads();
    for (int off = 1; off < 1024; off <<= 1) {
        int u = (t >= off) ? s[t - off] : 0;
        __syncthreads();
        s[t] += u;
        __syncthreads();
    }
    if (t < nPart) part[t] = (t == 0) ? 0 : s[t - 1];   // exclusive block offsets
}

__global__ __launch_bounds__(SCAN_BLOCK) void scan_final_kernel(const int* __restrict__ deg,
                                                                const int* __restrict__ part,
                                                                int* __restrict__ row_ptr, int N) {
    __shared__ int s[SCAN_BLOCK];
    int t = threadIdx.x;
    int i = blockIdx.x * SCAN_BLOCK + t;
    int v = (i < N) ? deg[i] : 0;
    s[t] = v;
    __syncthreads();
    #pragma unroll
    for (int off = 1; off < SCAN_BLOCK; off <<= 1) {
        int u = (t >= off) ? s[t - off] : 0;
        __syncthreads();
        s[t] += u;
        __syncthreads();
    }
    int incl = s[t];
    int base = part[blockIdx.x];
    if (i < N) row_ptr[i] = base + incl - v;
    if (i == N - 1) row_ptr[N] = base + incl;
}

__global__ __launch_bounds__(256) void scatter_kernel(const int* __restrict__ src,
                                                      const int* __restrict__ dst,
                                                      int E, int N,
                                                      const int* __restrict__ row_ptr,
                                                      int* __restrict__ cursor,
                                                      int* __restrict__ col_src) {
    int e = blockIdx.x * 256 + threadIdx.x;
    int Etot = E + N;
    if (e >= Etot) return;
    int d, s;
    if (e < E) { d = dst[e]; s = src[e]; } else { d = e - E; s = e - E; }
    int pos = atomicAdd(&cursor[d], 1);
    col_src[row_ptr[d] + pos] = s;
}

// ---------------- GEMM: register-blocked 8x8 outer product ----------------
// Y[N,128] = X[N,128] @ W[128,128]. Block = 128 thr (2 waves), tile 64 rows.
// Per thread: 8 rows x 8 cols (cols lx*4..+3 and 64+lx*4..+3).
// Xs transposed [k][row] padded to 68 (16B-aligned rows, conflict-free reads);
// Wt [k][col]: 16 addrs over 256B span -> 2-way conflict (free).
__global__ __launch_bounds__(128) void gemm_rb_kernel(const float* __restrict__ X,
                                                      const float* __restrict__ W,
                                                      float* __restrict__ Y, int N) {
    __shared__ float Xs[BK][68];
    __shared__ float Wt[BK][128];
    const int t = threadIdx.x;
    const int r0 = blockIdx.x * 64;
    const int lane = t & 63, w = t >> 6;
    const int lx = lane & 15, ly = lane >> 4;
    const int row_base = w * 32 + ly * 8;      // tile-local row of acc[0]
    const int c1 = lx * 4, c2 = 64 + lx * 4;   // two col chunks

    float acc[8][8];
    #pragma unroll
    for (int i = 0; i < 8; ++i)
        #pragma unroll
        for (int j = 0; j < 8; ++j) acc[i][j] = 0.f;

    for (int kt = 0; kt < 128; kt += BK) {
        __syncthreads();
        // stage X tile (64 rows x BK) transposed: idx -> row=idx>>3, k4=idx&7
        #pragma unroll
        for (int i = 0; i < 4; ++i) {
            int idx = i * 128 + t;
            int row = idx >> 3, k4 = idx & 7;
            int gr = r0 + row;
            float4 g = make_float4(0.f, 0.f, 0.f, 0.f);
            if (gr < N) g = *(const float4*)(X + (size_t)gr * 128 + kt + k4 * 4);
            Xs[k4 * 4 + 0][row] = g.x;
            Xs[k4 * 4 + 1][row] = g.y;
            Xs[k4 * 4 + 2][row] = g.z;
            Xs[k4 * 4 + 3][row] = g.w;
        }
        // stage W tile (BK x 128) straight: idx -> wr=idx>>5, c4=idx&31
        #pragma unroll
        for (int i = 0; i < 8; ++i) {
            int idx = i * 128 + t;
            int wr = idx >> 5, c4 = idx & 31;
            *(float4*)&Wt[wr][c4 * 4] = *(const float4*)(W + (size_t)(kt + wr) * 128 + c4 * 4);
        }
        __syncthreads();

        #pragma unroll 8
        for (int k = 0; k < BK; ++k) {
            float4 a0 = *(const float4*)&Xs[k][row_base];
            float4 a1 = *(const float4*)&Xs[k][row_base + 4];
            float4 b0 = *(const float4*)&Wt[k][c1];
            float4 b1 = *(const float4*)&Wt[k][c2];
            float a[8] = {a0.x, a0.y, a0.z, a0.w, a1.x, a1.y, a1.z, a1.w};
            float b[8] = {b0.x, b0.y, b0.z, b0.w, b1.x, b1.y, b1.z, b1.w};
            #pragma unroll
            for (int i = 0; i < 8; ++i)
                #pragma unroll
                for (int j = 0; j < 8; ++j)
                    acc[i][j] = fmaf(a[i], b[j], acc[i][j]);
        }
    }

    #pragma unroll
    for (int i = 0; i < 8; ++i) {
        int gr = r0 + row_base + i;
        if (gr < N) {
            *(float4*)(Y + (size_t)gr * 128 + c1) =
                make_float4(acc[i][0], acc[i][1], acc[i][2], acc[i][3]);
            *(float4*)(Y + (size_t)gr * 128 + c2) =
                make_float4(acc[i][4], acc[i][5], acc[i][6], acc[i][7]);
        }
    }
}

// ---------------- attention dots, layer 1 (H=8, C=16) ----------------
__global__ __launch_bounds__(256) void attdot1_kernel(const float* __restrict__ xh,
                                                      const float* __restrict__ attS,
                                                      const float* __restrict__ attD,
                                                      float* __restrict__ asrc,
                                                      float* __restrict__ adst, int N) {
    int node = blockIdx.x * 4 + (threadIdx.x >> 6);
    int lane = threadIdx.x & 63;
    if (node >= N) return;
    const float* row = xh + (size_t)node * 128;
    float x1 = row[lane], x2 = row[lane + 64];
    float s1 = x1 * attS[lane], s2 = x2 * attS[lane + 64];
    float d1 = x1 * attD[lane], d2 = x2 * attD[lane + 64];
    #pragma unroll
    for (int off = 8; off >= 1; off >>= 1) {
        s1 += __shfl_xor(s1, off, 64);
        s2 += __shfl_xor(s2, off, 64);
        d1 += __shfl_xor(d1, off, 64);
        d2 += __shfl_xor(d2, off, 64);
    }
    if ((lane & 15) == 0) {
        int h = lane >> 4;
        asrc[node * 8 + h]     = s1;
        asrc[node * 8 + h + 4] = s2;
        adst[node * 8 + h]     = d1;
        adst[node * 8 + h + 4] = d2;
    }
}

// ---------------- attention dots, layer 2 (H=1, C=128) ----------------
__global__ __launch_bounds__(256) void attdot2_kernel(const float* __restrict__ xh,
                                                      const float* __restrict__ attS,
                                                      const float* __restrict__ attD,
                                                      float* __restrict__ asrc,
                                                      float* __restrict__ adst, int N) {
    int node = blockIdx.x * 4 + (threadIdx.x >> 6);
    int lane = threadIdx.x & 63;
    if (node >= N) return;
    const float* row = xh + (size_t)node * 128;
    float x1 = row[lane], x2 = row[lane + 64];
    float ts = x1 * attS[lane] + x2 * attS[lane + 64];
    float td = x1 * attD[lane] + x2 * attD[lane + 64];
    #pragma unroll
    for (int off = 32; off >= 1; off >>= 1) {
        ts += __shfl_xor(ts, off, 64);
        td += __shfl_xor(td, off, 64);
    }
    if (lane == 0) { asrc[node] = ts; adst[node] = td; }
}

// ---------------- layer-1 aggregation: online softmax, one wave per node ----------------
__global__ __launch_bounds__(256) void agg1_kernel(const float* __restrict__ xh,
                                                   const float* __restrict__ asrc,
                                                   const float* __restrict__ adst,
                                                   const int* __restrict__ row_ptr,
                                                   const int* __restrict__ col_src,
                                                   const float* __restrict__ b1,
                                                   float* __restrict__ out, int N) {
    int node = blockIdx.x * 4 + (threadIdx.x >> 6);
    int lane = threadIdx.x & 63;
    if (node >= N) return;
    int h1 = lane >> 4;                 // head of value v1=lane; v2=lane+64 -> head h1+4
    float ad1 = adst[node * 8 + h1];
    float ad2 = adst[node * 8 + h1 + 4];
    int beg = row_ptr[node], end = row_ptr[node + 1];
    float m1 = -INFINITY, m2 = -INFINITY;
    float s1 = 0.f, s2 = 0.f, a1 = 0.f, a2 = 0.f;
    for (int e = beg; e < end; ++e) {
        int sv = col_src[e];
        float e1 = asrc[sv * 8 + h1] + ad1;
        float e2 = asrc[sv * 8 + h1 + 4] + ad2;
        e1 = (e1 > 0.f) ? e1 : NEG_SLOPE * e1;
        e2 = (e2 > 0.f) ? e2 : NEG_SLOPE * e2;
        float x1 = xh[(size_t)sv * 128 + lane];
        float x2 = xh[(size_t)sv * 128 + lane + 64];
        if (e1 > m1) { float r = __expf(m1 - e1); s1 *= r; a1 *= r; m1 = e1; }
        float p1 = __expf(e1 - m1);
        s1 += p1; a1 = fmaf(p1, x1, a1);
        if (e2 > m2) { float r = __expf(m2 - e2); s2 *= r; a2 *= r; m2 = e2; }
        float p2 = __expf(e2 - m2);
        s2 += p2; a2 = fmaf(p2, x2, a2);
    }
    float o1 = a1 / s1 + b1[lane];
    float o2 = a2 / s2 + b1[lane + 64];
    // ELU
    o1 = (o1 > 0.f) ? o1 : (__expf(o1) - 1.f);
    o2 = (o2 > 0.f) ? o2 : (__expf(o2) - 1.f);
    out[(size_t)node * 128 + lane]      = o1;
    out[(size_t)node * 128 + lane + 64] = o2;
}

// ---------------- layer-2 aggregation (H=1) ----------------
__global__ __launch_bounds__(256) void agg2_kernel(const float* __restrict__ xh,
                                                   const float* __restrict__ asrc,
                                                   const float* __restrict__ adst,
                                                   const int* __restrict__ row_ptr,
                                                   const int* __restrict__ col_src,
                                                   const float* __restrict__ b2,
                                                   float* __restrict__ out, int N) {
    int node = blockIdx.x * 4 + (threadIdx.x >> 6);
    int lane = threadIdx.x & 63;
    if (node >= N) return;
    float ad = adst[node];
    int beg = row_ptr[node], end = row_ptr[node + 1];
    float m = -INFINITY, s = 0.f, a1 = 0.f, a2 = 0.f;
    for (int e = beg; e < end; ++e) {
        int sv = col_src[e];
        float al = asrc[sv] + ad;
        al = (al > 0.f) ? al : NEG_SLOPE * al;
        float x1 = xh[(size_t)sv * 128 + lane];
        float x2 = xh[(size_t)sv * 128 + lane + 64];
        if (al > m) { float r = __expf(m - al); s *= r; a1 *= r; a2 *= r; m = al; }
        float p = __expf(al - m);
        s += p;
        a1 = fmaf(p, x1, a1);
        a2 = fmaf(p, x2, a2);
    }
    out[(size_t)node * 128 + lane]      = a1 / s + b2[lane];
    out[(size_t)node * 128 + lane + 64] = a2 / s + b2[lane + 64];
}

// ---------------- launch ----------------
extern "C" void kernel_launch(void* const* d_in, const int* in_sizes, int n_in,
                              void* d_out, int out_size, void* d_ws, size_t ws_size,
                              hipStream_t stream) {
    const float* x        = (const float*)d_in[0];
    const int*   src      = (const int*)d_in[1];
    const int*   dst      = (const int*)d_in[2];
    const float* W1       = (const float*)d_in[3];
    const float* att_src1 = (const float*)d_in[4];
    const float* att_dst1 = (const float*)d_in[5];
    const float* b1       = (const float*)d_in[6];
    const float* W2       = (const float*)d_in[7];
    const float* att_src2 = (const float*)d_in[8];
    const float* att_dst2 = (const float*)d_in[9];
    const float* b2       = (const float*)d_in[10];

    const int N = in_sizes[0] / 128;
    const int E = in_sizes[1];
    const int Etot = E + N;

    float* fws   = (float*)d_ws;
    float* xh    = fws;                    // N*128 (reused for both layers)
    float* asrc1 = xh + (size_t)N * 128;   // N*8
    float* adst1 = asrc1 + (size_t)N * 8;  // N*8
    float* asrc2 = adst1 + (size_t)N * 8;  // N
    float* adst2 = asrc2 + N;              // N
    int*   deg     = (int*)(adst2 + N);    // N
    int*   cursor  = deg + N;              // N
    int*   row_ptr = cursor + N;           // N+1
    int*   col_src = row_ptr + N + 1;      // Etot
    int*   part    = col_src + Etot;       // <=1024

    float* h = (float*)d_out;              // layer-1 output lives in d_out

    const int nodeBlocks = (N + 3) / 4;
    const int edgeBlocks = (Etot + 255) / 256;
    const int gemmBlocks = (N + 63) / 64;
    const int scanBlocks = (N + SCAN_BLOCK - 1) / SCAN_BLOCK;   // 196 <= 1024

    // CSR build (shared by both layers)
    zero_int_kernel<<<(2 * N + 255) / 256, 256, 0, stream>>>(deg, 2 * N);
    count_deg_kernel<<<edgeBlocks, 256, 0, stream>>>(dst, E, N, deg);
    deg_partial_kernel<<<scanBlocks, SCAN_BLOCK, 0, stream>>>(deg, part, N);
    scan_part_kernel<<<1, 1024, 0, stream>>>(part, scanBlocks);
    scan_final_kernel<<<scanBlocks, SCAN_BLOCK, 0, stream>>>(deg, part, row_ptr, N);
    scatter_kernel<<<edgeBlocks, 256, 0, stream>>>(src, dst, E, N, row_ptr, cursor, col_src);

    // Layer 1
    gemm_rb_kernel<<<gemmBlocks, 128, 0, stream>>>(x, W1, xh, N);
    attdot1_kernel<<<nodeBlocks, 256, 0, stream>>>(xh, att_src1, att_dst1, asrc1, adst1, N);
    agg1_kernel<<<nodeBlocks, 256, 0, stream>>>(xh, asrc1, adst1, row_ptr, col_src, b1, h, N);

    // Layer 2
    gemm_rb_kernel<<<gemmBlocks, 128, 0, stream>>>(h, W2, xh, N);
    attdot2_kernel<<<nodeBlocks, 256, 0, stream>>>(xh, att_src2, att_dst2, asrc2, adst2, N);
    agg2_kernel<<<nodeBlocks, 256, 0, stream>>>(xh, asrc2, adst2, row_ptr, col_src, b2, (float*)d_out, N);
}